// Round 1
// 287.350 us; speedup vs baseline: 1.0033x; 1.0033x over previous
//
#include <hip/hip_runtime.h>
#include <math.h>

#define NFRAMES 6
#define NBOX    1000000
#define TOTALBOX (NFRAMES * NBOX)          // 6,000,000 boxes
#define TOTALF4  (2 * TOTALBOX)            // 12,000,000 float4 records (32 B/box)
#define CHUNK_F4 256                        // float4s per wave-chunk (4 per lane)
#define CHUNK_BOX 128                       // boxes per wave-chunk
#define NCHUNKS  (TOTALF4 / CHUNK_F4)       // 46,875 — EXACT, no tail
#define BLOCK    256
#define NBLOCKS  2048                       // 8 blocks/CU x 256 CU; grid-stride covers rest
#define NWAVES   (NBLOCKS * (BLOCK / 64))   // 8192 waves

// W = 1.85 + 0.5, H = 4.084 + 0.5
#define HALF_W  (2.35f * 0.5f)
#define HALF_H  (4.584f * 0.5f)

// quad_perm [1,0,3,2] -> swap lanes 2k <-> 2k+1. Pure-VALU cross-lane (no LDS pipe).
__device__ __forceinline__ float dpp_swap_pair(float x) {
    return __int_as_float(__builtin_amdgcn_update_dpp(
        0, __float_as_int(x), 0xB1, 0xF, 0xF, true));
}

__global__ __launch_bounds__(BLOCK) void CollisionLoss_55327768708655_kernel(
    const float* __restrict__ traj,     // (1, F, 2)
    const float* __restrict__ gt,       // (1, F, 3)
    const float* __restrict__ corners,  // (F, N, 4, 2)
    const int*   __restrict__ mask,     // (F, N) bool stored as int32
    float* __restrict__ partials)       // NBLOCKS floats in d_ws
{
    // --- 6 frame AABBs -> LDS as float4 {xa1, ya1, xa2, ya2} ---
    __shared__ float4 s_frame[NFRAMES];
    if (threadIdx.x < NFRAMES) {
        int f = threadIdx.x;
        float x  = traj[f * 2 + 0];
        float y  = traj[f * 2 + 1];
        float th = gt[f * 3 + 2];
        float c = cosf(th), s = sinf(th);
        float ex = fabsf(c) * HALF_W + fabsf(s) * HALF_H;  // AABB half-extents of rotated rect
        float ey = fabsf(s) * HALF_W + fabsf(c) * HALF_H;
        s_frame[f] = make_float4(x + ex, y + ey, x - ex, y - ey);
    }
    __syncthreads();

    const float4* __restrict__ cp = (const float4*)corners;
    const int lane = threadIdx.x & 63;
    const int k    = lane >> 1;                       // box-within-32 index for this lane pair
    const int wid  = blockIdx.x * (BLOCK / 64) + (threadIdx.x >> 6);

    float acc = 0.0f;
    // Wave-granularity grid-stride over exact 256-float4 chunks: every
    // dwordx4 load instruction covers a contiguous aligned 1 KiB (lane i -> base + i*16B).
    for (int chunk = wid; chunk < NCHUNKS; chunk += NWAVES) {
        const float4* base = cp + (size_t)chunk * CHUNK_F4 + lane;
        const int basebox  = chunk * CHUNK_BOX;
        #pragma unroll
        for (int j = 0; j < 4; ++j) {
            float4 v = base[j * 64];                  // fully coalesced
            // partial extents of this half-box (2 corners)
            float pxmax = fmaxf(v.x, v.z), pxmin = fminf(v.x, v.z);
            float pymax = fmaxf(v.y, v.w), pymin = fminf(v.y, v.w);
            // combine with partner lane's half-box (lanes 2k,2k+1 hold one box)
            float xb1 = fmaxf(pxmax, dpp_swap_pair(pxmax));
            float xb2 = fminf(pxmin, dpp_swap_pair(pxmin));
            float yb1 = fmaxf(pymax, dpp_swap_pair(pymax));
            float yb2 = fminf(pymin, dpp_swap_pair(pymin));

            int b = basebox + j * 32 + k;             // global box index
            int f = (int)((unsigned)b / (unsigned)NBOX);  // magic-mul division
            float4 fr = s_frame[f];

            float w = fminf(fr.x, xb1) - fmaxf(fr.z, xb2);
            float h = fminf(fr.y, yb1) - fmaxf(fr.w, yb2);
            float a = fmaxf(w, 0.0f) * fmaxf(h, 0.0f);
            // both lanes of the pair compute the identical area; each adds half -> exact
            acc += mask[b] ? 0.5f * a : 0.0f;
        }
    }

    // --- wave-64 shuffle reduce -> LDS -> one store per block ---
    #pragma unroll
    for (int off = 32; off > 0; off >>= 1)
        acc += __shfl_down(acc, off, 64);
    __shared__ float s_part[BLOCK / 64];
    if (lane == 0) s_part[threadIdx.x >> 6] = acc;
    __syncthreads();
    if (threadIdx.x == 0)
        partials[blockIdx.x] = s_part[0] + s_part[1] + s_part[2] + s_part[3];
}

__global__ __launch_bounds__(BLOCK) void finalize_kernel(
    const float* __restrict__ partials, float* __restrict__ out)
{
    float acc = 0.0f;
    for (int i = threadIdx.x; i < NBLOCKS; i += BLOCK)
        acc += partials[i];
    #pragma unroll
    for (int off = 32; off > 0; off >>= 1)
        acc += __shfl_down(acc, off, 64);
    __shared__ float s_part[BLOCK / 64];
    int lane = threadIdx.x & 63;
    int wave = threadIdx.x >> 6;
    if (lane == 0) s_part[wave] = acc;
    __syncthreads();
    if (threadIdx.x == 0)
        out[0] = s_part[0] + s_part[1] + s_part[2] + s_part[3];  // WEIGHT == 1.0
}

extern "C" void kernel_launch(void* const* d_in, const int* in_sizes, int n_in,
                              void* d_out, int out_size, void* d_ws, size_t ws_size,
                              hipStream_t stream) {
    const float* traj     = (const float*)d_in[0];  // sdc_traj_all (1,F,2)
    const float* gt       = (const float*)d_in[1];  // sdc_planning_gt (1,F,3)
    // d_in[2] = sdc_planning_gt_mask — unused by the reference
    const float* corners  = (const float*)d_in[3];  // future_gt_corners (F,N,4,2)
    const int*   mask     = (const int*)d_in[4];    // box_mask (F,N) bool -> int32
    float* partials       = (float*)d_ws;           // NBLOCKS * 4 B (every slot overwritten)
    float* out            = (float*)d_out;

    CollisionLoss_55327768708655_kernel<<<NBLOCKS, BLOCK, 0, stream>>>(
        traj, gt, corners, mask, partials);
    finalize_kernel<<<1, BLOCK, 0, stream>>>(partials, out);
}